// Round 7
// baseline (454.873 us; speedup 1.0000x reference)
//
#include <hip/hip_runtime.h>
#include <stdint.h>
#include <stddef.h>

// Problem constants
#define T_ 512
#define B_ 256
#define IN_ 292
#define H_ 128
#define G4_ 512     // 4*H
#define TB_ 131072  // T_*B_
#define LCH 16      // time-chunk length for the segment scan
#define NCH 32      // number of chunks (T_/LCH)
#define KP_ 320     // K padded to 10*32

typedef short bf16x8 __attribute__((ext_vector_type(8)));
typedef float f32x4 __attribute__((ext_vector_type(4)));

__device__ __forceinline__ unsigned short f2bf(float f) {
  unsigned u = __float_as_uint(f);
  u += 0x7FFFu + ((u >> 16) & 1u);   // RTNE
  return (unsigned short)(u >> 16);
}
__device__ __forceinline__ float bf2f(unsigned short s) {
  return __uint_as_float(((unsigned)s) << 16);
}
// two fp32 -> packed bf16 pair (round-half-up). 1.5 VALU ops/elem.
__device__ __forceinline__ unsigned bfpack2(float a, float b) {
  unsigned ua = __float_as_uint(a) + 0x8000u;
  unsigned ub = __float_as_uint(b) + 0x8000u;
  return __builtin_amdgcn_perm(ub, ua, 0x07060302u);  // [ub.hi16 : ua.hi16]
}
__device__ __forceinline__ float sigf(float x) {
  return __builtin_amdgcn_rcpf(1.0f + __expf(-x));
}
__device__ __forceinline__ float tanhf_(float x) {
  return 1.0f - 2.0f * __builtin_amdgcn_rcpf(__expf(2.0f * x) + 1.0f);
}
// LDS-only barrier: lgkmcnt(0)+s_barrier, leaves global loads/stores in flight.
__device__ __forceinline__ void barrier_lds() {
  asm volatile("s_waitcnt lgkmcnt(0)\n\ts_barrier" ::: "memory");
}
// load one lane's 4 cell-quads (32 B contiguous): pr[r] = {i,f,g,o} of cell r.
__device__ __forceinline__ void load_pr(const unsigned short* p, ushort4* pr) {
  union { uint4 v; ushort4 s[2]; } a, b;
  a.v = *(const uint4*)p;
  b.v = *(const uint4*)(p + 8);
  pr[0] = a.s[0]; pr[1] = a.s[1]; pr[2] = b.s[0]; pr[3] = b.s[1];
}

// ---------------------------------------------------------------------------
// K0w: W_ih fp32 [512][292] -> Wf, FRAG-MAJOR bf16 layout:
//   Wf[((g16*10 + it)*64 + lane)*8 .. +8] = row jj = 16*g16 + (lane&15),
//   k = it*32 + (lane>>4)*8 .. +8, with jj -> W_ih row (jj&3)*128 + (jj>>2)
//   (jj = cell*4 + gate). Each k1 af-load is 64 lanes x 16B fully contiguous.
//   Zero-pads k 292..319. Also emits reordered bias2[jj] fp32.
// ---------------------------------------------------------------------------
__global__ __launch_bounds__(256) void k0w_cvt(
    const float* __restrict__ Wih, const float* __restrict__ bih,
    const float* __restrict__ bhh, unsigned short* __restrict__ Wf,
    float* __restrict__ bias2) {
  const int g = blockIdx.x * 256 + threadIdx.x;  // 0..20479
  const int lane = g & 63;
  const int rest = g >> 6;          // 0..319
  const int it = rest % 10;
  const int g16 = rest / 10;        // 0..31
  const int jj = g16 * 16 + (lane & 15);
  const int src = (jj & 3) * 128 + (jj >> 2);
  const int c0 = it * 32 + (lane >> 4) * 8;
  if (g < 512) {
    const int sb = (g & 3) * 128 + (g >> 2);
    bias2[g] = bih[sb] + bhh[sb];
  }
  float4 a = {0.f, 0.f, 0.f, 0.f}, b = {0.f, 0.f, 0.f, 0.f};
  const float* p = Wih + (size_t)src * IN_ + c0;
  if (c0 + 8 <= IN_) { a = *(const float4*)p; b = *(const float4*)(p + 4); }
  else if (c0 < IN_) { a = *(const float4*)p; }  // c0==288: cols 288..291
  uint4 o;
  o.x = bfpack2(a.x, a.y); o.y = bfpack2(a.z, a.w);
  o.z = bfpack2(b.x, b.y); o.w = bfpack2(b.z, b.w);
  *(uint4*)&Wf[(size_t)g * 8] = o;  // g == (g16*10+it)*64 + lane
}

// ---------------------------------------------------------------------------
// K1 v9: pre2[m][jj] (bf16) = x @ W^T + bias2.
// Round-6 post-mortem: per-iteration time was identical at 1 and 2 blocks/CU
// -> the stage->barrier->consume structure ITSELF was the cap (memory queue
// drained every iteration; v7's spill accident proved 4.3 TB/s is reachable
// when requests flow ungated). Fix: NO x staging, NO main-loop barriers.
//  - each wave loads its x fragments DIRECTLY global->reg. The block's 8 KB
//    x window/iter is L1-resident (12 KB/block w/ W, 2 blocks = 24 KB < 32);
//    wave 0 misses to L2/HBM, waves 1..7 hit L1. HBM traffic unchanged.
//  - 16 waves/CU of free-running TLP hide all load latency; the only
//    barriers left are in the epilogue.
//  - tail k-tile (cols 288..291) peeled: loads exactly 16 B at q==0, which
//    for the last row ends exactly at the buffer end (no OOB).
//  - acc[4][4]=64 AGPR, ~120 regs/wave, __launch_bounds__(512,4) -> 2 blocks.
// ---------------------------------------------------------------------------
__global__ __launch_bounds__(512, 4) void k1_pregemm(
    const float* __restrict__ x, const unsigned short* __restrict__ Wf,
    const float* __restrict__ bias2, unsigned short* __restrict__ pre2) {
  __shared__ unsigned short ep[16 * 520];     // 16.25 KB epilogue staging

  const int tid = threadIdx.x;
  const int w = tid >> 6;        // 0..7: jj group [64w, 64w+64)
  const int lane = tid & 63;
  const int l15 = lane & 15;
  const int q = lane >> 4;
  const int m0 = blockIdx.x * 64;

  // W frag base for this wave: af(s,kt) at wfbase + (s*10+kt)*512 ushorts
  const unsigned short* wfbase = Wf + ((size_t)(4 * w) * 10 * 64 + lane) * 8;

  // per-lane x base pointers for the 4 m-fragments (row = m0+16ms+l15)
  const float* xp0 = x + (size_t)(m0 + l15) * IN_ + q * 8;
  const float* xp1 = xp0 + (size_t)16 * IN_;
  const float* xp2 = xp0 + (size_t)32 * IN_;
  const float* xp3 = xp0 + (size_t)48 * IN_;

  f32x4 acc[4][4];
#pragma unroll
  for (int s = 0; s < 4; s++)
#pragma unroll
    for (int ms = 0; ms < 4; ms++) acc[s][ms] = (f32x4){0.f, 0.f, 0.f, 0.f};

#pragma unroll 1
  for (int kt = 0; kt < 9; ++kt) {
    // W frags for this k-tile (L2-hot, 1 KB contiguous per instr)
    bf16x8 af[4];
#pragma unroll
    for (int s = 0; s < 4; s++)
      af[s] = *(const bf16x8*)(wfbase + (s * 10 + kt) * 512);
    // x fragments: direct global->reg (L1-hot after first wave), cvt bf16
    bf16x8 bfr[4];
#pragma unroll
    for (int ms = 0; ms < 4; ms++) {
      const float* xp = (ms == 0) ? xp0 : (ms == 1) ? xp1 : (ms == 2) ? xp2 : xp3;
      const float4 u0 = *(const float4*)(xp + kt * 32);
      const float4 u1 = *(const float4*)(xp + kt * 32 + 4);
      union { unsigned u[4]; bf16x8 v; } cv;
      cv.u[0] = bfpack2(u0.x, u0.y); cv.u[1] = bfpack2(u0.z, u0.w);
      cv.u[2] = bfpack2(u1.x, u1.y); cv.u[3] = bfpack2(u1.z, u1.w);
      bfr[ms] = cv.v;
    }
#pragma unroll
    for (int s = 0; s < 4; s++)
#pragma unroll
      for (int ms = 0; ms < 4; ms++)
        acc[s][ms] = __builtin_amdgcn_mfma_f32_16x16x32_bf16(
            af[s], bfr[ms], acc[s][ms], 0, 0, 0);
  }
  {  // peeled tail k-tile (cols 288..291 real, 292..319 zero-padded in W)
    bf16x8 af[4];
#pragma unroll
    for (int s = 0; s < 4; s++)
      af[s] = *(const bf16x8*)(wfbase + (s * 10 + 9) * 512);
    const float4 z = {0.f, 0.f, 0.f, 0.f};
    bf16x8 bfr[4];
#pragma unroll
    for (int ms = 0; ms < 4; ms++) {
      const float* xp = (ms == 0) ? xp0 : (ms == 1) ? xp1 : (ms == 2) ? xp2 : xp3;
      // q==0: xp == row base; load cols 288..291 (ends exactly at row end)
      const float4 u0 = (q == 0) ? *(const float4*)(xp + 288) : z;
      union { unsigned u[4]; bf16x8 v; } cv;
      cv.u[0] = bfpack2(u0.x, u0.y); cv.u[1] = bfpack2(u0.z, u0.w);
      cv.u[2] = 0u; cv.u[3] = 0u;
      bfr[ms] = cv.v;
    }
#pragma unroll
    for (int s = 0; s < 4; s++)
#pragma unroll
      for (int ms = 0; ms < 4; ms++)
        acc[s][ms] = __builtin_amdgcn_mfma_f32_16x16x32_bf16(
            af[s], bfr[ms], acc[s][ms], 0, 0, 0);
  }
  __syncthreads();

  // epilogue: 4 stages x 16 rows via ep; full 1KB-row stores.
  float4 bb[4];
#pragma unroll
  for (int s = 0; s < 4; s++)
    bb[s] = *(const float4*)&bias2[64 * w + 16 * s + 4 * q];

#pragma unroll
  for (int st = 0; st < 4; ++st) {
    // all 8 waves contribute acc[.][st] -> rows [16st, 16st+16)
#pragma unroll
    for (int s = 0; s < 4; ++s) {
      uint2 v;
      v.x = bfpack2(acc[s][st][0] + bb[s].x, acc[s][st][1] + bb[s].y);
      v.y = bfpack2(acc[s][st][2] + bb[s].z, acc[s][st][3] + bb[s].w);
      *(uint2*)&ep[l15 * 520 + 64 * w + 16 * s + 4 * q] = v;
    }
    barrier_lds();
    // full-row stores: wave w -> stage rows w and w+8 (1 KB contiguous each)
#pragma unroll
    for (int p = 0; p < 2; ++p) {
      const int r = 8 * p + w;
      uint4 v = *(const uint4*)&ep[r * 520 + lane * 8];
      *(uint4*)&pre2[((size_t)(m0 + 16 * st + r) << 9) + lane * 8] = v;
    }
    barrier_lds();  // reads done before next stage overwrites ep
  }
}

// ---------------------------------------------------------------------------
// Segment-scan LSTM (exact for any done; fast because P(reset)=0.5).
// pre2 layout: element m*512 + cell*4 + gate -> one 32B load per lane gives
// pr[r] = {i,f,g,o} of cell kcell+r.  LCH=16 -> 512 blocks (2/CU).
// ---------------------------------------------------------------------------
__global__ __launch_bounds__(512) void k2a_chunk(
    const unsigned short* __restrict__ pre2, const float* __restrict__ Whh,
    const int* __restrict__ done, unsigned short* __restrict__ hidden,
    unsigned short* __restrict__ hfin, float* __restrict__ cfin) {
  __shared__ unsigned short hs[2][16 * 136];
  __shared__ int dns[LCH * 16];

  const int bg = blockIdx.x & 15;
  const int ck = blockIdx.x >> 4;
  const int t0 = ck * LCH;
  const int tid = threadIdx.x;
  const int w = tid >> 6;
  const int lane = tid & 63;
  const int l15 = lane & 15;
  const int q = lane >> 4;
  const int bglob = bg * 16 + l15;
  const int kcell = 16 * w + 4 * q;
  const int kq16 = kcell * 4;  // element offset of this lane's 4 cell-quads

  if (tid < LCH * 16) {
    const int r = tid >> 4, c = tid & 15;
    dns[tid] = done[(size_t)(t0 + r) * B_ + bg * 16 + c];
  }

  bf16x8 wf[4][4];
#pragma unroll
  for (int tI = 0; tI < 4; tI++) {
    const int jg = 16 * (w + 8 * tI) + l15;
#pragma unroll
    for (int kc = 0; kc < 4; kc++) {
      const float* p = Whh + (size_t)jg * H_ + kc * 32 + q * 8;
      float4 u0 = *(const float4*)p;
      float4 u1 = *(const float4*)(p + 4);
      bf16x8 r;
      r[0]=(short)f2bf(u0.x); r[1]=(short)f2bf(u0.y); r[2]=(short)f2bf(u0.z); r[3]=(short)f2bf(u0.w);
      r[4]=(short)f2bf(u1.x); r[5]=(short)f2bf(u1.y); r[6]=(short)f2bf(u1.z); r[7]=(short)f2bf(u1.w);
      wf[tI][kc] = r;
    }
  }

  float c_[4] = {0.f, 0.f, 0.f, 0.f};
  {
    const int b = tid >> 5, k = (tid & 31) * 4;
    *(ushort4*)&hs[0][b * 136 + k] = (ushort4){0, 0, 0, 0};
  }
  bool vld = false;
  __syncthreads();

  ushort4 pr[4], prn[4];
  load_pr(pre2 + ((size_t)t0 * B_ + bglob) * G4_ + kq16, pr);
  load_pr(pre2 + ((size_t)(t0 + 1) * B_ + bglob) * G4_ + kq16, prn);

  ushort4 hw = {0, 0, 0, 0};
#pragma unroll 1
  for (int u = 0; u < LCH; u++) {
    const int t = t0 + u;
    ushort4 pr2[4];
    const int un = (u + 2 < LCH) ? u + 2 : LCH - 1;
    load_pr(pre2 + ((size_t)(t0 + un) * B_ + bglob) * G4_ + kq16, pr2);

    const int dn = dns[u * 16 + l15];
    vld = vld || (dn != 0);

    const unsigned short* hb = hs[u & 1];
    bf16x8 hf[4];
#pragma unroll
    for (int kc = 0; kc < 4; kc++) {
      bf16x8 v = *(const bf16x8*)&hb[l15 * 136 + kc * 32 + q * 8];
      if (dn) v = (bf16x8){0, 0, 0, 0, 0, 0, 0, 0};
      hf[kc] = v;
    }

    f32x4 acc[4];
#pragma unroll
    for (int tI = 0; tI < 4; tI++) acc[tI] = (f32x4){0.f, 0.f, 0.f, 0.f};
#pragma unroll
    for (int tI = 0; tI < 4; tI++)
#pragma unroll
      for (int kc = 0; kc < 4; kc++)
        acc[tI] = __builtin_amdgcn_mfma_f32_16x16x32_bf16(
            wf[tI][kc], hf[kc], acc[tI], 0, 0, 0);

    const float m = dn ? 0.0f : 1.0f;
    float hv[4];
#pragma unroll
    for (int r = 0; r < 4; r++) {
      const float iv = acc[0][r] + bf2f(pr[r].x);
      const float fv = acc[1][r] + bf2f(pr[r].y);
      const float gv = acc[2][r] + bf2f(pr[r].z);
      const float ov = acc[3][r] + bf2f(pr[r].w);
      float cc = c_[r] * m;
      cc = sigf(fv) * cc + sigf(iv) * tanhf_(gv);
      c_[r] = cc;
      hv[r] = sigf(ov) * tanhf_(cc);
    }
    uint2 hp = {bfpack2(hv[0], hv[1]), bfpack2(hv[2], hv[3])};
    hw = *(ushort4*)&hp;
    *(uint2*)&hs[(u + 1) & 1][l15 * 136 + kcell] = hp;
    if (vld)
      *(uint2*)&hidden[((size_t)t * B_ + bglob) * H_ + kcell] = hp;
#pragma unroll
    for (int tI = 0; tI < 4; tI++) { pr[tI] = prn[tI]; prn[tI] = pr2[tI]; }
    barrier_lds();
  }

  *(ushort4*)&hfin[((size_t)ck * B_ + bglob) * H_ + kcell] = hw;
  float4 cv = {c_[0], c_[1], c_[2], c_[3]};
  *(float4*)&cfin[((size_t)ck * B_ + bglob) * H_ + kcell] = cv;
}

__global__ __launch_bounds__(512) void k2b_par(
    const unsigned short* __restrict__ pre2, const float* __restrict__ Whh,
    const float* __restrict__ h0, const float* __restrict__ c0,
    const int* __restrict__ done, unsigned short* __restrict__ hidden,
    const unsigned short* __restrict__ hfin, const float* __restrict__ cfin,
    int* __restrict__ needfix) {
  __shared__ unsigned short hs[2][16 * 136];
  __shared__ int dns[LCH * 16];

  const int bg = blockIdx.x & 15;
  const int ck = blockIdx.x >> 4;
  const int t0 = ck * LCH;
  const int tid = threadIdx.x;
  const int w = tid >> 6;
  const int lane = tid & 63;
  const int l15 = lane & 15;
  const int q = lane >> 4;
  const int bglob = bg * 16 + l15;
  const int kcell = 16 * w + 4 * q;
  const int kq16 = kcell * 4;

  if (tid < LCH * 16) {
    const int r = tid >> 4, c = tid & 15;
    dns[tid] = done[(size_t)(t0 + r) * B_ + bg * 16 + c];
  }

  bf16x8 wf[4][4];
#pragma unroll
  for (int tI = 0; tI < 4; tI++) {
    const int jg = 16 * (w + 8 * tI) + l15;
#pragma unroll
    for (int kc = 0; kc < 4; kc++) {
      const float* p = Whh + (size_t)jg * H_ + kc * 32 + q * 8;
      float4 u0 = *(const float4*)p;
      float4 u1 = *(const float4*)(p + 4);
      bf16x8 r;
      r[0]=(short)f2bf(u0.x); r[1]=(short)f2bf(u0.y); r[2]=(short)f2bf(u0.z); r[3]=(short)f2bf(u0.w);
      r[4]=(short)f2bf(u1.x); r[5]=(short)f2bf(u1.y); r[6]=(short)f2bf(u1.z); r[7]=(short)f2bf(u1.w);
      wf[tI][kc] = r;
    }
  }

  float c_[4];
  {
    const int b = tid >> 5, k = (tid & 31) * 4;
    if (ck == 0) {
      float4 hv = *(const float4*)(h0 + (size_t)(bg * 16 + b) * H_ + k);
      uint2 hp = {bfpack2(hv.x, hv.y), bfpack2(hv.z, hv.w)};
      *(uint2*)&hs[0][b * 136 + k] = hp;
      float4 cv = *(const float4*)(c0 + (size_t)bglob * H_ + kcell);
      c_[0] = cv.x; c_[1] = cv.y; c_[2] = cv.z; c_[3] = cv.w;
    } else {
      ushort4 hv = *(const ushort4*)&hfin[((size_t)(ck - 1) * B_ + bg * 16 + b) * H_ + k];
      *(ushort4*)&hs[0][b * 136 + k] = hv;
      float4 cv = *(const float4*)&cfin[((size_t)(ck - 1) * B_ + bglob) * H_ + kcell];
      c_[0] = cv.x; c_[1] = cv.y; c_[2] = cv.z; c_[3] = cv.w;
    }
  }
  int cur = 0;
  bool act = true;
  __syncthreads();

  ushort4 pr[4], prn[4];
  load_pr(pre2 + ((size_t)t0 * B_ + bglob) * G4_ + kq16, pr);
  load_pr(pre2 + ((size_t)(t0 + 1) * B_ + bglob) * G4_ + kq16, prn);

#pragma unroll 1
  for (int u = 0; u < LCH; u++) {
    const int t = t0 + u;
    const int dn = dns[u * 16 + l15];
    const bool nact = act && (dn == 0);
    if (__ballot(nact) == 0ULL) { act = false; break; }
    act = nact;

    ushort4 pr2[4];
    const int un = (u + 2 < LCH) ? u + 2 : LCH - 1;
    load_pr(pre2 + ((size_t)(t0 + un) * B_ + bglob) * G4_ + kq16, pr2);

    const unsigned short* hb = hs[cur];
    bf16x8 hf[4];
#pragma unroll
    for (int kc = 0; kc < 4; kc++)
      hf[kc] = *(const bf16x8*)&hb[l15 * 136 + kc * 32 + q * 8];

    f32x4 acc[4];
#pragma unroll
    for (int tI = 0; tI < 4; tI++) acc[tI] = (f32x4){0.f, 0.f, 0.f, 0.f};
#pragma unroll
    for (int tI = 0; tI < 4; tI++)
#pragma unroll
      for (int kc = 0; kc < 4; kc++)
        acc[tI] = __builtin_amdgcn_mfma_f32_16x16x32_bf16(
            wf[tI][kc], hf[kc], acc[tI], 0, 0, 0);

    float hv[4];
#pragma unroll
    for (int r = 0; r < 4; r++) {
      const float iv = acc[0][r] + bf2f(pr[r].x);
      const float fv = acc[1][r] + bf2f(pr[r].y);
      const float gv = acc[2][r] + bf2f(pr[r].z);
      const float ov = acc[3][r] + bf2f(pr[r].w);
      float cc = sigf(fv) * c_[r] + sigf(iv) * tanhf_(gv);
      c_[r] = cc;
      hv[r] = sigf(ov) * tanhf_(cc);
    }
    uint2 hp = {bfpack2(hv[0], hv[1]), bfpack2(hv[2], hv[3])};
    *(uint2*)&hs[cur ^ 1][l15 * 136 + kcell] = hp;
    if (act)
      *(uint2*)&hidden[((size_t)t * B_ + bglob) * H_ + kcell] = hp;
#pragma unroll
    for (int tI = 0; tI < 4; tI++) { pr[tI] = prn[tI]; prn[tI] = pr2[tI]; }
    barrier_lds();
    cur ^= 1;
  }

  if (tid == 0) needfix[blockIdx.x] = (__ballot(act) != 0ULL) ? 1 : 0;
}

// Sequential guard: exact fallback, expected to exit immediately.
__global__ __launch_bounds__(512) void k2c_guard(
    const unsigned short* __restrict__ pre2, const float* __restrict__ Whh,
    const float* __restrict__ h0, const float* __restrict__ c0,
    const int* __restrict__ done, unsigned short* __restrict__ hidden,
    const unsigned short* __restrict__ hfin, const float* __restrict__ cfin,
    const int* __restrict__ needfix) {
  const int bg = blockIdx.x;
  bool dirty = false;
  for (int c2 = 0; c2 < NCH - 1; c2++) dirty |= (needfix[c2 * 16 + bg] != 0);
  if (!dirty) return;

  __shared__ unsigned short hs[2][16 * 136];
  __shared__ int dns[T_ * 16];

  const int tid = threadIdx.x;
  const int w = tid >> 6;
  const int lane = tid & 63;
  const int l15 = lane & 15;
  const int q = lane >> 4;
  const int bglob = bg * 16 + l15;
  const int kcell = 16 * w + 4 * q;
  const int kq16 = kcell * 4;

  {
    const int* p = done + (size_t)tid * B_ + bg * 16;
    *(int4*)&dns[tid * 16]      = *(const int4*)(p);
    *(int4*)&dns[tid * 16 + 4]  = *(const int4*)(p + 4);
    *(int4*)&dns[tid * 16 + 8]  = *(const int4*)(p + 8);
    *(int4*)&dns[tid * 16 + 12] = *(const int4*)(p + 12);
  }

  bf16x8 wf[4][4];
#pragma unroll
  for (int tI = 0; tI < 4; tI++) {
    const int jg = 16 * (w + 8 * tI) + l15;
#pragma unroll
    for (int kc = 0; kc < 4; kc++) {
      const float* p = Whh + (size_t)jg * H_ + kc * 32 + q * 8;
      float4 u0 = *(const float4*)p;
      float4 u1 = *(const float4*)(p + 4);
      bf16x8 r;
      r[0]=(short)f2bf(u0.x); r[1]=(short)f2bf(u0.y); r[2]=(short)f2bf(u0.z); r[3]=(short)f2bf(u0.w);
      r[4]=(short)f2bf(u1.x); r[5]=(short)f2bf(u1.y); r[6]=(short)f2bf(u1.z); r[7]=(short)f2bf(u1.w);
      wf[tI][kc] = r;
    }
  }

  float c_[4];
  {
    float4 cv = *(const float4*)(c0 + (size_t)bglob * H_ + kcell);
    c_[0] = cv.x; c_[1] = cv.y; c_[2] = cv.z; c_[3] = cv.w;
    const int b = tid >> 5, k = (tid & 31) * 4;
    float4 hv = *(const float4*)(h0 + (size_t)(bg * 16 + b) * H_ + k);
    uint2 hp = {bfpack2(hv.x, hv.y), bfpack2(hv.z, hv.w)};
    *(uint2*)&hs[0][b * 136 + k] = hp;
  }
  int cur = 0;
  __syncthreads();

#pragma unroll 1
  for (int ck = 0; ck < NCH; ck++) {
    const int t0 = ck * LCH;
    bool act = true;

    ushort4 pr[4];
    load_pr(pre2 + ((size_t)t0 * B_ + bglob) * G4_ + kq16, pr);

#pragma unroll 1
    for (int u = 0; u < LCH; u++) {
      const int t = t0 + u;
      const int dn = dns[t * 16 + l15];
      const bool nact = act && (dn == 0);
      if (__ballot(nact) == 0ULL) { act = false; break; }
      act = nact;

      ushort4 prn[4];
      const int un = (u + 1 < LCH) ? u + 1 : LCH - 1;
      load_pr(pre2 + ((size_t)(t0 + un) * B_ + bglob) * G4_ + kq16, prn);

      const unsigned short* hb = hs[cur];
      bf16x8 hf[4];
#pragma unroll
      for (int kc = 0; kc < 4; kc++)
        hf[kc] = *(const bf16x8*)&hb[l15 * 136 + kc * 32 + q * 8];

      f32x4 acc[4];
#pragma unroll
      for (int tI = 0; tI < 4; tI++) acc[tI] = (f32x4){0.f, 0.f, 0.f, 0.f};
#pragma unroll
      for (int tI = 0; tI < 4; tI++)
#pragma unroll
        for (int kc = 0; kc < 4; kc++)
          acc[tI] = __builtin_amdgcn_mfma_f32_16x16x32_bf16(
              wf[tI][kc], hf[kc], acc[tI], 0, 0, 0);

      float hv[4];
#pragma unroll
      for (int r = 0; r < 4; r++) {
        const float iv = acc[0][r] + bf2f(pr[r].x);
        const float fv = acc[1][r] + bf2f(pr[r].y);
        const float gv = acc[2][r] + bf2f(pr[r].z);
        const float ov = acc[3][r] + bf2f(pr[r].w);
        float cc = sigf(fv) * c_[r] + sigf(iv) * tanhf_(gv);
        c_[r] = cc;
        hv[r] = sigf(ov) * tanhf_(cc);
      }
      uint2 hp = {bfpack2(hv[0], hv[1]), bfpack2(hv[2], hv[3])};
      *(uint2*)&hs[cur ^ 1][l15 * 136 + kcell] = hp;
      if (act)
        *(uint2*)&hidden[((size_t)t * B_ + bglob) * H_ + kcell] = hp;
#pragma unroll
      for (int tI = 0; tI < 4; tI++) pr[tI] = prn[tI];
      barrier_lds();
      cur ^= 1;
    }

    if (!act) {
      ushort4 hv = *(const ushort4*)&hfin[((size_t)ck * B_ + bglob) * H_ + kcell];
      float4 cv = *(const float4*)&cfin[((size_t)ck * B_ + bglob) * H_ + kcell];
      c_[0] = cv.x; c_[1] = cv.y; c_[2] = cv.z; c_[3] = cv.w;
      *(ushort4*)&hs[cur][l15 * 136 + kcell] = hv;
    }
    barrier_lds();
  }
}

// ---------------------------------------------------------------------------
// K3: out[T*B][13] = hidden @ [W_pi; W_v]^T + [b_pi; b_v]   (unchanged)
// ---------------------------------------------------------------------------
__global__ __launch_bounds__(256) void k3_head(
    const unsigned short* __restrict__ hidden, const float* __restrict__ Wpi,
    const float* __restrict__ bpi, const float* __restrict__ Wv,
    const float* __restrict__ bv, float* __restrict__ out) {
  __shared__ unsigned short hs3[64 * 136];
  __shared__ float bias_s[16];

  const int tid = threadIdx.x;
  const int w = tid >> 6;
  const int lane = tid & 63;
  const int l15 = lane & 15;
  const int q = lane >> 4;
  const int m0 = blockIdx.x * 64;

  if (tid < 16) bias_s[tid] = (tid < 12) ? bpi[tid] : ((tid == 12) ? bv[0] : 0.f);

  bf16x8 wf3[4];
#pragma unroll
  for (int kc = 0; kc < 4; kc++) {
    float4 u0 = {0.f, 0.f, 0.f, 0.f}, u1 = {0.f, 0.f, 0.f, 0.f};
    if (l15 < 12) {
      const float* p = Wpi + (size_t)l15 * H_ + kc * 32 + q * 8;
      u0 = *(const float4*)p; u1 = *(const float4*)(p + 4);
    } else if (l15 == 12) {
      const float* p = Wv + kc * 32 + q * 8;
      u0 = *(const float4*)p; u1 = *(const float4*)(p + 4);
    }
    bf16x8 r;
    r[0]=(short)f2bf(u0.x); r[1]=(short)f2bf(u0.y); r[2]=(short)f2bf(u0.z); r[3]=(short)f2bf(u0.w);
    r[4]=(short)f2bf(u1.x); r[5]=(short)f2bf(u1.y); r[6]=(short)f2bf(u1.z); r[7]=(short)f2bf(u1.w);
    wf3[kc] = r;
  }

  {
    const int row = tid >> 2, ks = (tid & 3) * 32;
    const unsigned short* p = hidden + (size_t)(m0 + row) * H_ + ks;
#pragma unroll
    for (int i = 0; i < 4; i++)
      *(uint4*)&hs3[row * 136 + ks + i * 8] = *(const uint4*)(p + i * 8);
  }
  __syncthreads();

  f32x4 acc = (f32x4){0.f, 0.f, 0.f, 0.f};
#pragma unroll
  for (int kc = 0; kc < 4; kc++) {
    bf16x8 hf = *(bf16x8*)&hs3[(16 * w + l15) * 136 + kc * 32 + q * 8];
    acc = __builtin_amdgcn_mfma_f32_16x16x32_bf16(wf3[kc], hf, acc, 0, 0, 0);
  }

  const float4 bb = *(float4*)&bias_s[4 * q];
  const int m = m0 + 16 * w + l15;
  const size_t ro = (size_t)m * 13;
  float v0 = acc[0] + bb.x, v1 = acc[1] + bb.y, v2 = acc[2] + bb.z, v3 = acc[3] + bb.w;
  if (q < 3) {
    out[ro + 4 * q + 0] = v0;
    out[ro + 4 * q + 1] = v1;
    out[ro + 4 * q + 2] = v2;
    out[ro + 4 * q + 3] = v3;
  } else {
    out[ro + 12] = v0;
  }
}

// ---------------------------------------------------------------------------
// Workspace (ws, 167.8 MB):
//   pre2   bf16 [131072][512] @ 0            (cell-major-quad layout)
//   hidden bf16 [131072][128] @ 134,217,728
// Scratch in d_out (6.5 MB, overwritten by K3 at the end; NCH=32 packing):
//   Wf bf16 [320K] @ 0
//   bias2 fp32 [2K] @ 327,680
//   needfix int [2K] @ 331,776
//   hfin bf16 [32][256][128] (2 MB) @ 524,288
//   cfin fp32 [32][256][128] (4 MB) @ 2,621,440  (ends exactly at 6,815,744)
// ---------------------------------------------------------------------------
extern "C" void kernel_launch(void* const* d_in, const int* in_sizes, int n_in,
                              void* d_out, int out_size, void* d_ws, size_t ws_size,
                              hipStream_t stream) {
  const float* x    = (const float*)d_in[0];
  const int* done   = (const int*)d_in[1];
  const float* h0   = (const float*)d_in[2];
  const float* c0   = (const float*)d_in[3];
  const float* Wih  = (const float*)d_in[4];
  const float* Whh  = (const float*)d_in[5];
  const float* bih  = (const float*)d_in[6];
  const float* bhh  = (const float*)d_in[7];
  const float* Wpi  = (const float*)d_in[8];
  const float* bpi  = (const float*)d_in[9];
  const float* Wv   = (const float*)d_in[10];
  const float* bv   = (const float*)d_in[11];
  (void)in_sizes; (void)n_in; (void)out_size; (void)ws_size;

  unsigned short* pre2 = (unsigned short*)d_ws;
  unsigned short* hidden = pre2 + (size_t)TB_ * G4_;
  unsigned short* Wf   = (unsigned short*)d_out;
  float* bias2         = (float*)((char*)d_out + 327680u);
  int* needfix         = (int*)((char*)d_out + 331776u);
  unsigned short* hfin = (unsigned short*)((char*)d_out + 524288u);
  float* cfin          = (float*)((char*)d_out + 2621440u);
  float* out = (float*)d_out;

  k0w_cvt<<<80, 256, 0, stream>>>(Wih, bih, bhh, Wf, bias2);
  k1_pregemm<<<TB_ / 64, 512, 0, stream>>>(x, Wf, bias2, pre2);
  k2a_chunk<<<NCH * 16, 512, 0, stream>>>(pre2, Whh, done, hidden, hfin, cfin);
  k2b_par<<<NCH * 16, 512, 0, stream>>>(pre2, Whh, h0, c0, done, hidden, hfin, cfin, needfix);
  k2c_guard<<<16, 512, 0, stream>>>(pre2, Whh, h0, c0, done, hidden, hfin, cfin, needfix);
  k3_head<<<TB_ / 64, 256, 0, stream>>>(hidden, Wpi, bpi, Wv, bv, out);
}

// Round 8
// 372.187 us; speedup vs baseline: 1.2222x; 1.2222x over previous
//
#include <hip/hip_runtime.h>
#include <stdint.h>
#include <stddef.h>

// Problem constants
#define T_ 512
#define B_ 256
#define IN_ 292
#define H_ 128
#define G4_ 512     // 4*H
#define TB_ 131072  // T_*B_
#define LCH 32      // time-chunk length for the segment scan
#define NCH 16      // number of chunks (T_/LCH)
#define KP_ 320     // K padded to 10*32

typedef short bf16x8 __attribute__((ext_vector_type(8)));
typedef float f32x4 __attribute__((ext_vector_type(4)));

__device__ __forceinline__ unsigned short f2bf(float f) {
  unsigned u = __float_as_uint(f);
  u += 0x7FFFu + ((u >> 16) & 1u);   // RTNE
  return (unsigned short)(u >> 16);
}
__device__ __forceinline__ float bf2f(unsigned short s) {
  return __uint_as_float(((unsigned)s) << 16);
}
// two fp32 -> packed bf16 pair (round-half-up). 1.5 VALU ops/elem.
__device__ __forceinline__ unsigned bfpack2(float a, float b) {
  unsigned ua = __float_as_uint(a) + 0x8000u;
  unsigned ub = __float_as_uint(b) + 0x8000u;
  return __builtin_amdgcn_perm(ub, ua, 0x07060302u);  // [ub.hi16 : ua.hi16]
}
__device__ __forceinline__ float sigf(float x) {
  return __builtin_amdgcn_rcpf(1.0f + __expf(-x));
}
__device__ __forceinline__ float tanhf_(float x) {
  return 1.0f - 2.0f * __builtin_amdgcn_rcpf(__expf(2.0f * x) + 1.0f);
}
// LDS-only barrier: lgkmcnt(0)+s_barrier, leaves global loads/stores in flight.
__device__ __forceinline__ void barrier_lds() {
  asm volatile("s_waitcnt lgkmcnt(0)\n\ts_barrier" ::: "memory");
}
// async 16B global->LDS (direct-to-LDS DMA, no VGPR round trip)
__device__ __forceinline__ void gload_lds16(const float* g, float* l) {
  __builtin_amdgcn_global_load_lds(
      (const __attribute__((address_space(1))) void*)g,
      (__attribute__((address_space(3))) void*)l, 16, 0, 0);
}
// load one lane's 4 cell-quads (32 B contiguous): pr[r] = {i,f,g,o} of cell r.
__device__ __forceinline__ void load_pr(const unsigned short* p, ushort4* pr) {
  union { uint4 v; ushort4 s[2]; } a, b;
  a.v = *(const uint4*)p;
  b.v = *(const uint4*)(p + 8);
  pr[0] = a.s[0]; pr[1] = a.s[1]; pr[2] = b.s[0]; pr[3] = b.s[1];
}

// ---------------------------------------------------------------------------
// K0w: W_ih fp32 [512][292] -> Wf, FRAG-MAJOR bf16 layout:
//   Wf[((g16*10 + it)*64 + lane)*8 .. +8] = row jj = 16*g16 + (lane&15),
//   k = it*32 + (lane>>4)*8 .. +8, with jj -> W_ih row (jj&3)*128 + (jj>>2)
//   (jj = cell*4 + gate). Each k1 af-load is 64 lanes x 16B fully contiguous.
//   Zero-pads k 292..319 (this zeroing also neutralizes k1's tail-garbage x).
//   Also emits reordered bias2[jj] fp32.
// ---------------------------------------------------------------------------
__global__ __launch_bounds__(256) void k0w_cvt(
    const float* __restrict__ Wih, const float* __restrict__ bih,
    const float* __restrict__ bhh, unsigned short* __restrict__ Wf,
    float* __restrict__ bias2) {
  const int g = blockIdx.x * 256 + threadIdx.x;  // 0..20479
  const int lane = g & 63;
  const int rest = g >> 6;          // 0..319
  const int it = rest % 10;
  const int g16 = rest / 10;        // 0..31
  const int jj = g16 * 16 + (lane & 15);
  const int src = (jj & 3) * 128 + (jj >> 2);
  const int c0 = it * 32 + (lane >> 4) * 8;
  if (g < 512) {
    const int sb = (g & 3) * 128 + (g >> 2);
    bias2[g] = bih[sb] + bhh[sb];
  }
  float4 a = {0.f, 0.f, 0.f, 0.f}, b = {0.f, 0.f, 0.f, 0.f};
  const float* p = Wih + (size_t)src * IN_ + c0;
  if (c0 + 8 <= IN_) { a = *(const float4*)p; b = *(const float4*)(p + 4); }
  else if (c0 < IN_) { a = *(const float4*)p; }  // c0==288: cols 288..291
  uint4 o;
  o.x = bfpack2(a.x, a.y); o.y = bfpack2(a.z, a.w);
  o.z = bfpack2(b.x, b.y); o.w = bfpack2(b.z, b.w);
  *(uint4*)&Wf[(size_t)g * 8] = o;  // g == (g16*10+it)*64 + lane
}

// ---------------------------------------------------------------------------
// K1 v10: pre2[m][jj] (bf16) = x @ W^T + bias2.
// Round-7 post-mortem: direct global x loads are 16-row gathers (regressed);
// the stage->barrier->consume loop caps at ~23% HBM duty (1-tile depth).
// Fix: stage the ENTIRE 64x292 fp32 x tile in ONE gload burst (10 loads/lane
// in flight = max pipeline depth), sync ONCE, then a barrier-free k-loop:
//  - k-loop reads only LDS (x) + L2-hot Wf; 10 uniform iterations, no
//    conditionals: tail k>=292 reads in-bounds garbage that multiplies
//    ZERO-PADDED W columns -> contributes 0.
//  - natural row stride 292 floats == 4 mod 32 banks -> ds_read_b128s are
//    bank-balanced; NO swizzle needed (the 32-float rows of v5/v8 were the
//    conflict case).
//  - epilogue ALIASES the x buffer (after a barrier): block LDS = 74.75 KB
//    -> 2 resident blocks/CU; block B's burst+compute overlaps block A's
//    drain. ~120 unified regs (64 acc AGPR) under LB(512,4)'s 128 cap.
// ---------------------------------------------------------------------------
__global__ __launch_bounds__(512, 4) void k1_pregemm(
    const float* __restrict__ x, const unsigned short* __restrict__ Wf,
    const float* __restrict__ bias2, unsigned short* __restrict__ pre2) {
  __shared__ float xtf[64 * 292];   // 74.75 KB; epilogue staging aliases it

  const int tid = threadIdx.x;
  const int w = tid >> 6;        // 0..7: jj group [64w, 64w+64)
  const int lane = tid & 63;
  const int l15 = lane & 15;
  const int q = lane >> 4;
  const int m0 = blockIdx.x * 64;

  // W frag base for this wave: af(s,kt) at wfbase + (s*10+kt)*512 ushorts
  const unsigned short* wfbase = Wf + ((size_t)(4 * w) * 10 * 64 + lane) * 8;

  // ---- stage the ENTIRE x tile: one burst, 9.125 rounds of 512x16B ----
  // quad g (g=0..4671) = row g/73, in-row quad g%73 (73 quads = 292 floats).
  // LDS dst = xtf + g*4: wave-uniform base + lane*16B (gload requirement).
#pragma unroll
  for (int r = 0; r < 9; ++r) {
    const int g = r * 512 + tid;
    const int row = g / 73, qir = g % 73;
    gload_lds16(x + (size_t)(m0 + row) * IN_ + qir * 4, xtf + g * 4);
  }
  if (tid < 64) {                          // tail 64 quads: row 63, quads 9..72
    const int g = 4608 + tid;
    gload_lds16(x + (size_t)(m0 + 63) * IN_ + (g % 73) * 4, xtf + g * 4);
  }

  f32x4 acc[4][4];
#pragma unroll
  for (int s = 0; s < 4; s++)
#pragma unroll
    for (int ms = 0; ms < 4; ms++) acc[s][ms] = (f32x4){0.f, 0.f, 0.f, 0.f};

  bf16x8 af[4];
#pragma unroll
  for (int s = 0; s < 4; s++)
    af[s] = *(const bf16x8*)(wfbase + (s * 10 + 0) * 512);

  __syncthreads();  // single drain; co-resident block computes through it

  // ---- k-loop: LDS + L2 only, NO barriers ----
#pragma unroll 1
  for (int kt = 0; kt < 10; ++kt) {
    bf16x8 afn[4];
    if (kt < 9) {
#pragma unroll
      for (int s = 0; s < 4; s++)
        afn[s] = *(const bf16x8*)(wfbase + (s * 10 + kt + 1) * 512);
    }
    // x frags from LDS (fp32 -> bf16). kt==9: only q==0/u0 (cols 288..291)
    // is real; other positions read in-row garbage * zero-padded W = 0.
    const int col0 = (kt < 9) ? kt * 32 + q * 8 : (q == 0 ? 288 : 0);
    const int col1 = (kt < 9) ? col0 + 4 : 4;
    bf16x8 bfr[4];
#pragma unroll
    for (int ms = 0; ms < 4; ms++) {
      const float* rp = xtf + (16 * ms + l15) * IN_;
      const float4 u0 = *(const float4*)(rp + col0);
      const float4 u1 = *(const float4*)(rp + col1);
      union { unsigned u[4]; bf16x8 v; } cv;
      cv.u[0] = bfpack2(u0.x, u0.y); cv.u[1] = bfpack2(u0.z, u0.w);
      cv.u[2] = bfpack2(u1.x, u1.y); cv.u[3] = bfpack2(u1.z, u1.w);
      bfr[ms] = cv.v;
    }
#pragma unroll
    for (int s = 0; s < 4; s++)
#pragma unroll
      for (int ms = 0; ms < 4; ms++)
        acc[s][ms] = __builtin_amdgcn_mfma_f32_16x16x32_bf16(
            af[s], bfr[ms], acc[s][ms], 0, 0, 0);
#pragma unroll
    for (int s = 0; s < 4; s++) af[s] = afn[s];
  }

  __syncthreads();  // all xtf reads complete before aliasing as epilogue buf
  unsigned short* ep = (unsigned short*)xtf;   // 16*520 ushorts = 16.6 KB

  // epilogue: 4 stages x 16 rows via ep; full 1KB-row contiguous stores.
  float4 bb[4];
#pragma unroll
  for (int s = 0; s < 4; s++)
    bb[s] = *(const float4*)&bias2[64 * w + 16 * s + 4 * q];

#pragma unroll
  for (int st = 0; st < 4; ++st) {
    // all 8 waves contribute acc[.][st] -> rows [16st, 16st+16)
#pragma unroll
    for (int s = 0; s < 4; ++s) {
      uint2 v;
      v.x = bfpack2(acc[s][st][0] + bb[s].x, acc[s][st][1] + bb[s].y);
      v.y = bfpack2(acc[s][st][2] + bb[s].z, acc[s][st][3] + bb[s].w);
      *(uint2*)&ep[l15 * 520 + 64 * w + 16 * s + 4 * q] = v;
    }
    barrier_lds();
    // full-row stores: wave w -> stage rows w and w+8 (1 KB contiguous each)
#pragma unroll
    for (int p = 0; p < 2; ++p) {
      const int r = 8 * p + w;
      uint4 v = *(const uint4*)&ep[r * 520 + lane * 8];
      *(uint4*)&pre2[((size_t)(m0 + 16 * st + r) << 9) + lane * 8] = v;
    }
    barrier_lds();  // reads done before next stage overwrites ep
  }
}

// ---------------------------------------------------------------------------
// Segment-scan LSTM (exact for any done; fast because P(reset)=0.5).
// pre2 layout: element m*512 + cell*4 + gate -> one 32B load per lane gives
// pr[r] = {i,f,g,o} of cell kcell+r.  (round-3 config: LCH=32, best measured)
// ---------------------------------------------------------------------------
__global__ __launch_bounds__(512) void k2a_chunk(
    const unsigned short* __restrict__ pre2, const float* __restrict__ Whh,
    const int* __restrict__ done, unsigned short* __restrict__ hidden,
    unsigned short* __restrict__ hfin, float* __restrict__ cfin) {
  __shared__ unsigned short hs[2][16 * 136];
  __shared__ int dns[LCH * 16];

  const int bg = blockIdx.x & 15;
  const int ck = blockIdx.x >> 4;
  const int t0 = ck * LCH;
  const int tid = threadIdx.x;
  const int w = tid >> 6;
  const int lane = tid & 63;
  const int l15 = lane & 15;
  const int q = lane >> 4;
  const int bglob = bg * 16 + l15;
  const int kcell = 16 * w + 4 * q;
  const int kq16 = kcell * 4;  // element offset of this lane's 4 cell-quads

  {
    const int r = tid >> 4, c = tid & 15;
    dns[tid] = done[(size_t)(t0 + r) * B_ + bg * 16 + c];
  }

  bf16x8 wf[4][4];
#pragma unroll
  for (int tI = 0; tI < 4; tI++) {
    const int jg = 16 * (w + 8 * tI) + l15;
#pragma unroll
    for (int kc = 0; kc < 4; kc++) {
      const float* p = Whh + (size_t)jg * H_ + kc * 32 + q * 8;
      float4 u0 = *(const float4*)p;
      float4 u1 = *(const float4*)(p + 4);
      bf16x8 r;
      r[0]=(short)f2bf(u0.x); r[1]=(short)f2bf(u0.y); r[2]=(short)f2bf(u0.z); r[3]=(short)f2bf(u0.w);
      r[4]=(short)f2bf(u1.x); r[5]=(short)f2bf(u1.y); r[6]=(short)f2bf(u1.z); r[7]=(short)f2bf(u1.w);
      wf[tI][kc] = r;
    }
  }

  float c_[4] = {0.f, 0.f, 0.f, 0.f};
  {
    const int b = tid >> 5, k = (tid & 31) * 4;
    *(ushort4*)&hs[0][b * 136 + k] = (ushort4){0, 0, 0, 0};
  }
  bool vld = false;
  __syncthreads();

  ushort4 pr[4], prn[4];
  load_pr(pre2 + ((size_t)t0 * B_ + bglob) * G4_ + kq16, pr);
  load_pr(pre2 + ((size_t)(t0 + 1) * B_ + bglob) * G4_ + kq16, prn);

  ushort4 hw = {0, 0, 0, 0};
#pragma unroll 1
  for (int u = 0; u < LCH; u++) {
    const int t = t0 + u;
    ushort4 pr2[4];
    const int un = (u + 2 < LCH) ? u + 2 : LCH - 1;
    load_pr(pre2 + ((size_t)(t0 + un) * B_ + bglob) * G4_ + kq16, pr2);

    const int dn = dns[u * 16 + l15];
    vld = vld || (dn != 0);

    const unsigned short* hb = hs[u & 1];
    bf16x8 hf[4];
#pragma unroll
    for (int kc = 0; kc < 4; kc++) {
      bf16x8 v = *(const bf16x8*)&hb[l15 * 136 + kc * 32 + q * 8];
      if (dn) v = (bf16x8){0, 0, 0, 0, 0, 0, 0, 0};
      hf[kc] = v;
    }

    f32x4 acc[4];
#pragma unroll
    for (int tI = 0; tI < 4; tI++) acc[tI] = (f32x4){0.f, 0.f, 0.f, 0.f};
#pragma unroll
    for (int tI = 0; tI < 4; tI++)
#pragma unroll
      for (int kc = 0; kc < 4; kc++)
        acc[tI] = __builtin_amdgcn_mfma_f32_16x16x32_bf16(
            wf[tI][kc], hf[kc], acc[tI], 0, 0, 0);

    const float m = dn ? 0.0f : 1.0f;
    float hv[4];
#pragma unroll
    for (int r = 0; r < 4; r++) {
      const float iv = acc[0][r] + bf2f(pr[r].x);
      const float fv = acc[1][r] + bf2f(pr[r].y);
      const float gv = acc[2][r] + bf2f(pr[r].z);
      const float ov = acc[3][r] + bf2f(pr[r].w);
      float cc = c_[r] * m;
      cc = sigf(fv) * cc + sigf(iv) * tanhf_(gv);
      c_[r] = cc;
      hv[r] = sigf(ov) * tanhf_(cc);
    }
    uint2 hp = {bfpack2(hv[0], hv[1]), bfpack2(hv[2], hv[3])};
    hw = *(ushort4*)&hp;
    *(uint2*)&hs[(u + 1) & 1][l15 * 136 + kcell] = hp;
    if (vld)
      *(uint2*)&hidden[((size_t)t * B_ + bglob) * H_ + kcell] = hp;
#pragma unroll
    for (int tI = 0; tI < 4; tI++) { pr[tI] = prn[tI]; prn[tI] = pr2[tI]; }
    barrier_lds();
  }

  *(ushort4*)&hfin[((size_t)ck * B_ + bglob) * H_ + kcell] = hw;
  float4 cv = {c_[0], c_[1], c_[2], c_[3]};
  *(float4*)&cfin[((size_t)ck * B_ + bglob) * H_ + kcell] = cv;
}

__global__ __launch_bounds__(512) void k2b_par(
    const unsigned short* __restrict__ pre2, const float* __restrict__ Whh,
    const float* __restrict__ h0, const float* __restrict__ c0,
    const int* __restrict__ done, unsigned short* __restrict__ hidden,
    const unsigned short* __restrict__ hfin, const float* __restrict__ cfin,
    int* __restrict__ needfix) {
  __shared__ unsigned short hs[2][16 * 136];
  __shared__ int dns[LCH * 16];

  const int bg = blockIdx.x & 15;
  const int ck = blockIdx.x >> 4;
  const int t0 = ck * LCH;
  const int tid = threadIdx.x;
  const int w = tid >> 6;
  const int lane = tid & 63;
  const int l15 = lane & 15;
  const int q = lane >> 4;
  const int bglob = bg * 16 + l15;
  const int kcell = 16 * w + 4 * q;
  const int kq16 = kcell * 4;

  {
    const int r = tid >> 4, c = tid & 15;
    dns[tid] = done[(size_t)(t0 + r) * B_ + bg * 16 + c];
  }

  bf16x8 wf[4][4];
#pragma unroll
  for (int tI = 0; tI < 4; tI++) {
    const int jg = 16 * (w + 8 * tI) + l15;
#pragma unroll
    for (int kc = 0; kc < 4; kc++) {
      const float* p = Whh + (size_t)jg * H_ + kc * 32 + q * 8;
      float4 u0 = *(const float4*)p;
      float4 u1 = *(const float4*)(p + 4);
      bf16x8 r;
      r[0]=(short)f2bf(u0.x); r[1]=(short)f2bf(u0.y); r[2]=(short)f2bf(u0.z); r[3]=(short)f2bf(u0.w);
      r[4]=(short)f2bf(u1.x); r[5]=(short)f2bf(u1.y); r[6]=(short)f2bf(u1.z); r[7]=(short)f2bf(u1.w);
      wf[tI][kc] = r;
    }
  }

  float c_[4];
  {
    const int b = tid >> 5, k = (tid & 31) * 4;
    if (ck == 0) {
      float4 hv = *(const float4*)(h0 + (size_t)(bg * 16 + b) * H_ + k);
      uint2 hp = {bfpack2(hv.x, hv.y), bfpack2(hv.z, hv.w)};
      *(uint2*)&hs[0][b * 136 + k] = hp;
      float4 cv = *(const float4*)(c0 + (size_t)bglob * H_ + kcell);
      c_[0] = cv.x; c_[1] = cv.y; c_[2] = cv.z; c_[3] = cv.w;
    } else {
      ushort4 hv = *(const ushort4*)&hfin[((size_t)(ck - 1) * B_ + bg * 16 + b) * H_ + k];
      *(ushort4*)&hs[0][b * 136 + k] = hv;
      float4 cv = *(const float4*)&cfin[((size_t)(ck - 1) * B_ + bglob) * H_ + kcell];
      c_[0] = cv.x; c_[1] = cv.y; c_[2] = cv.z; c_[3] = cv.w;
    }
  }
  int cur = 0;
  bool act = true;
  __syncthreads();

  ushort4 pr[4], prn[4];
  load_pr(pre2 + ((size_t)t0 * B_ + bglob) * G4_ + kq16, pr);
  load_pr(pre2 + ((size_t)(t0 + 1) * B_ + bglob) * G4_ + kq16, prn);

#pragma unroll 1
  for (int u = 0; u < LCH; u++) {
    const int t = t0 + u;
    const int dn = dns[u * 16 + l15];
    const bool nact = act && (dn == 0);
    if (__ballot(nact) == 0ULL) { act = false; break; }
    act = nact;

    ushort4 pr2[4];
    const int un = (u + 2 < LCH) ? u + 2 : LCH - 1;
    load_pr(pre2 + ((size_t)(t0 + un) * B_ + bglob) * G4_ + kq16, pr2);

    const unsigned short* hb = hs[cur];
    bf16x8 hf[4];
#pragma unroll
    for (int kc = 0; kc < 4; kc++)
      hf[kc] = *(const bf16x8*)&hb[l15 * 136 + kc * 32 + q * 8];

    f32x4 acc[4];
#pragma unroll
    for (int tI = 0; tI < 4; tI++) acc[tI] = (f32x4){0.f, 0.f, 0.f, 0.f};
#pragma unroll
    for (int tI = 0; tI < 4; tI++)
#pragma unroll
      for (int kc = 0; kc < 4; kc++)
        acc[tI] = __builtin_amdgcn_mfma_f32_16x16x32_bf16(
            wf[tI][kc], hf[kc], acc[tI], 0, 0, 0);

    float hv[4];
#pragma unroll
    for (int r = 0; r < 4; r++) {
      const float iv = acc[0][r] + bf2f(pr[r].x);
      const float fv = acc[1][r] + bf2f(pr[r].y);
      const float gv = acc[2][r] + bf2f(pr[r].z);
      const float ov = acc[3][r] + bf2f(pr[r].w);
      float cc = sigf(fv) * c_[r] + sigf(iv) * tanhf_(gv);
      c_[r] = cc;
      hv[r] = sigf(ov) * tanhf_(cc);
    }
    uint2 hp = {bfpack2(hv[0], hv[1]), bfpack2(hv[2], hv[3])};
    *(uint2*)&hs[cur ^ 1][l15 * 136 + kcell] = hp;
    if (act)
      *(uint2*)&hidden[((size_t)t * B_ + bglob) * H_ + kcell] = hp;
#pragma unroll
    for (int tI = 0; tI < 4; tI++) { pr[tI] = prn[tI]; prn[tI] = pr2[tI]; }
    barrier_lds();
    cur ^= 1;
  }

  if (tid == 0) needfix[blockIdx.x] = (__ballot(act) != 0ULL) ? 1 : 0;
}

// Sequential guard: exact fallback, expected to exit immediately.
__global__ __launch_bounds__(512) void k2c_guard(
    const unsigned short* __restrict__ pre2, const float* __restrict__ Whh,
    const float* __restrict__ h0, const float* __restrict__ c0,
    const int* __restrict__ done, unsigned short* __restrict__ hidden,
    const unsigned short* __restrict__ hfin, const float* __restrict__ cfin,
    const int* __restrict__ needfix) {
  const int bg = blockIdx.x;
  bool dirty = false;
  for (int c2 = 0; c2 < NCH - 1; c2++) dirty |= (needfix[c2 * 16 + bg] != 0);
  if (!dirty) return;

  __shared__ unsigned short hs[2][16 * 136];
  __shared__ int dns[T_ * 16];

  const int tid = threadIdx.x;
  const int w = tid >> 6;
  const int lane = tid & 63;
  const int l15 = lane & 15;
  const int q = lane >> 4;
  const int bglob = bg * 16 + l15;
  const int kcell = 16 * w + 4 * q;
  const int kq16 = kcell * 4;

  {
    const int* p = done + (size_t)tid * B_ + bg * 16;
    *(int4*)&dns[tid * 16]      = *(const int4*)(p);
    *(int4*)&dns[tid * 16 + 4]  = *(const int4*)(p + 4);
    *(int4*)&dns[tid * 16 + 8]  = *(const int4*)(p + 8);
    *(int4*)&dns[tid * 16 + 12] = *(const int4*)(p + 12);
  }

  bf16x8 wf[4][4];
#pragma unroll
  for (int tI = 0; tI < 4; tI++) {
    const int jg = 16 * (w + 8 * tI) + l15;
#pragma unroll
    for (int kc = 0; kc < 4; kc++) {
      const float* p = Whh + (size_t)jg * H_ + kc * 32 + q * 8;
      float4 u0 = *(const float4*)p;
      float4 u1 = *(const float4*)(p + 4);
      bf16x8 r;
      r[0]=(short)f2bf(u0.x); r[1]=(short)f2bf(u0.y); r[2]=(short)f2bf(u0.z); r[3]=(short)f2bf(u0.w);
      r[4]=(short)f2bf(u1.x); r[5]=(short)f2bf(u1.y); r[6]=(short)f2bf(u1.z); r[7]=(short)f2bf(u1.w);
      wf[tI][kc] = r;
    }
  }

  float c_[4];
  {
    float4 cv = *(const float4*)(c0 + (size_t)bglob * H_ + kcell);
    c_[0] = cv.x; c_[1] = cv.y; c_[2] = cv.z; c_[3] = cv.w;
    const int b = tid >> 5, k = (tid & 31) * 4;
    float4 hv = *(const float4*)(h0 + (size_t)(bg * 16 + b) * H_ + k);
    uint2 hp = {bfpack2(hv.x, hv.y), bfpack2(hv.z, hv.w)};
    *(uint2*)&hs[0][b * 136 + k] = hp;
  }
  int cur = 0;
  __syncthreads();

#pragma unroll 1
  for (int ck = 0; ck < NCH; ck++) {
    const int t0 = ck * LCH;
    bool act = true;

    ushort4 pr[4];
    load_pr(pre2 + ((size_t)t0 * B_ + bglob) * G4_ + kq16, pr);

#pragma unroll 1
    for (int u = 0; u < LCH; u++) {
      const int t = t0 + u;
      const int dn = dns[t * 16 + l15];
      const bool nact = act && (dn == 0);
      if (__ballot(nact) == 0ULL) { act = false; break; }
      act = nact;

      ushort4 prn[4];
      const int un = (u + 1 < LCH) ? u + 1 : LCH - 1;
      load_pr(pre2 + ((size_t)(t0 + un) * B_ + bglob) * G4_ + kq16, prn);

      const unsigned short* hb = hs[cur];
      bf16x8 hf[4];
#pragma unroll
      for (int kc = 0; kc < 4; kc++)
        hf[kc] = *(const bf16x8*)&hb[l15 * 136 + kc * 32 + q * 8];

      f32x4 acc[4];
#pragma unroll
      for (int tI = 0; tI < 4; tI++) acc[tI] = (f32x4){0.f, 0.f, 0.f, 0.f};
#pragma unroll
      for (int tI = 0; tI < 4; tI++)
#pragma unroll
        for (int kc = 0; kc < 4; kc++)
          acc[tI] = __builtin_amdgcn_mfma_f32_16x16x32_bf16(
              wf[tI][kc], hf[kc], acc[tI], 0, 0, 0);

      float hv[4];
#pragma unroll
      for (int r = 0; r < 4; r++) {
        const float iv = acc[0][r] + bf2f(pr[r].x);
        const float fv = acc[1][r] + bf2f(pr[r].y);
        const float gv = acc[2][r] + bf2f(pr[r].z);
        const float ov = acc[3][r] + bf2f(pr[r].w);
        float cc = sigf(fv) * c_[r] + sigf(iv) * tanhf_(gv);
        c_[r] = cc;
        hv[r] = sigf(ov) * tanhf_(cc);
      }
      uint2 hp = {bfpack2(hv[0], hv[1]), bfpack2(hv[2], hv[3])};
      *(uint2*)&hs[cur ^ 1][l15 * 136 + kcell] = hp;
      if (act)
        *(uint2*)&hidden[((size_t)t * B_ + bglob) * H_ + kcell] = hp;
#pragma unroll
      for (int tI = 0; tI < 4; tI++) pr[tI] = prn[tI];
      barrier_lds();
      cur ^= 1;
    }

    if (!act) {
      ushort4 hv = *(const ushort4*)&hfin[((size_t)ck * B_ + bglob) * H_ + kcell];
      float4 cv = *(const float4*)&cfin[((size_t)ck * B_ + bglob) * H_ + kcell];
      c_[0] = cv.x; c_[1] = cv.y; c_[2] = cv.z; c_[3] = cv.w;
      *(ushort4*)&hs[cur][l15 * 136 + kcell] = hv;
    }
    barrier_lds();
  }
}

// ---------------------------------------------------------------------------
// K3: out[T*B][13] = hidden @ [W_pi; W_v]^T + [b_pi; b_v]   (unchanged)
// ---------------------------------------------------------------------------
__global__ __launch_bounds__(256) void k3_head(
    const unsigned short* __restrict__ hidden, const float* __restrict__ Wpi,
    const float* __restrict__ bpi, const float* __restrict__ Wv,
    const float* __restrict__ bv, float* __restrict__ out) {
  __shared__ unsigned short hs3[64 * 136];
  __shared__ float bias_s[16];

  const int tid = threadIdx.x;
  const int w = tid >> 6;
  const int lane = tid & 63;
  const int l15 = lane & 15;
  const int q = lane >> 4;
  const int m0 = blockIdx.x * 64;

  if (tid < 16) bias_s[tid] = (tid < 12) ? bpi[tid] : ((tid == 12) ? bv[0] : 0.f);

  bf16x8 wf3[4];
#pragma unroll
  for (int kc = 0; kc < 4; kc++) {
    float4 u0 = {0.f, 0.f, 0.f, 0.f}, u1 = {0.f, 0.f, 0.f, 0.f};
    if (l15 < 12) {
      const float* p = Wpi + (size_t)l15 * H_ + kc * 32 + q * 8;
      u0 = *(const float4*)p; u1 = *(const float4*)(p + 4);
    } else if (l15 == 12) {
      const float* p = Wv + kc * 32 + q * 8;
      u0 = *(const float4*)p; u1 = *(const float4*)(p + 4);
    }
    bf16x8 r;
    r[0]=(short)f2bf(u0.x); r[1]=(short)f2bf(u0.y); r[2]=(short)f2bf(u0.z); r[3]=(short)f2bf(u0.w);
    r[4]=(short)f2bf(u1.x); r[5]=(short)f2bf(u1.y); r[6]=(short)f2bf(u1.z); r[7]=(short)f2bf(u1.w);
    wf3[kc] = r;
  }

  {
    const int row = tid >> 2, ks = (tid & 3) * 32;
    const unsigned short* p = hidden + (size_t)(m0 + row) * H_ + ks;
#pragma unroll
    for (int i = 0; i < 4; i++)
      *(uint4*)&hs3[row * 136 + ks + i * 8] = *(const uint4*)(p + i * 8);
  }
  __syncthreads();

  f32x4 acc = (f32x4){0.f, 0.f, 0.f, 0.f};
#pragma unroll
  for (int kc = 0; kc < 4; kc++) {
    bf16x8 hf = *(bf16x8*)&hs3[(16 * w + l15) * 136 + kc * 32 + q * 8];
    acc = __builtin_amdgcn_mfma_f32_16x16x32_bf16(wf3[kc], hf, acc, 0, 0, 0);
  }

  const float4 bb = *(float4*)&bias_s[4 * q];
  const int m = m0 + 16 * w + l15;
  const size_t ro = (size_t)m * 13;
  float v0 = acc[0] + bb.x, v1 = acc[1] + bb.y, v2 = acc[2] + bb.z, v3 = acc[3] + bb.w;
  if (q < 3) {
    out[ro + 4 * q + 0] = v0;
    out[ro + 4 * q + 1] = v1;
    out[ro + 4 * q + 2] = v2;
    out[ro + 4 * q + 3] = v3;
  } else {
    out[ro + 12] = v0;
  }
}

// ---------------------------------------------------------------------------
// Workspace (ws, 167.8 MB):
//   pre2   bf16 [131072][512] @ 0            (cell-major-quad layout)
//   hidden bf16 [131072][128] @ 134,217,728
// Scratch in d_out (6.5 MB, overwritten by K3 at the end; NCH=16 packing):
//   Wf bf16 frag-major [320 KB] @ 0   bias2 fp32 [512] @ 512 KB
//   hfin @ 1 MB, cfin @ 2 MB, needfix @ 4 MB
// ---------------------------------------------------------------------------
extern "C" void kernel_launch(void* const* d_in, const int* in_sizes, int n_in,
                              void* d_out, int out_size, void* d_ws, size_t ws_size,
                              hipStream_t stream) {
  const float* x    = (const float*)d_in[0];
  const int* done   = (const int*)d_in[1];
  const float* h0   = (const float*)d_in[2];
  const float* c0   = (const float*)d_in[3];
  const float* Wih  = (const float*)d_in[4];
  const float* Whh  = (const float*)d_in[5];
  const float* bih  = (const float*)d_in[6];
  const float* bhh  = (const float*)d_in[7];
  const float* Wpi  = (const float*)d_in[8];
  const float* bpi  = (const float*)d_in[9];
  const float* Wv   = (const float*)d_in[10];
  const float* bv   = (const float*)d_in[11];
  (void)in_sizes; (void)n_in; (void)out_size; (void)ws_size;

  unsigned short* pre2 = (unsigned short*)d_ws;
  unsigned short* hidden = pre2 + (size_t)TB_ * G4_;
  unsigned short* Wf   = (unsigned short*)d_out;
  float* bias2         = (float*)((char*)d_out + (512u << 10));
  unsigned short* hfin = (unsigned short*)((char*)d_out + (1u << 20));
  float* cfin          = (float*)((char*)d_out + (2u << 20));
  int* needfix         = (int*)((char*)d_out + (4u << 20));
  float* out = (float*)d_out;

  k0w_cvt<<<80, 256, 0, stream>>>(Wih, bih, bhh, Wf, bias2);
  k1_pregemm<<<TB_ / 64, 512, 0, stream>>>(x, Wf, bias2, pre2);
  k2a_chunk<<<256, 512, 0, stream>>>(pre2, Whh, done, hidden, hfin, cfin);
  k2b_par<<<256, 512, 0, stream>>>(pre2, Whh, h0, c0, done, hidden, hfin, cfin, needfix);
  k2c_guard<<<16, 512, 0, stream>>>(pre2, Whh, h0, c0, done, hidden, hfin, cfin, needfix);
  k3_head<<<TB_ / 64, 256, 0, stream>>>(hidden, Wpi, bpi, Wv, bv, out);
}